// Round 1
// baseline (678.182 us; speedup 1.0000x reference)
//
#include <hip/hip_runtime.h>

// DomainAwareStructuralPrior: masks (128,1024,1024) f32 logits -> (128,) f32 scores.
// Pass 1: per-(image,row-chunk) integer sums of area / connectivity / perimeter.
// Pass 2: 128-thread scoring kernel.
//
// Sums are integer-valued and < 2^24, so the fp32 reference reductions are
// exact -> exact int accumulation here matches the reference exactly.

#define N_IMG 128
#define H 1024
#define W 1024
#define CHUNKS 16
#define ROWS (H / CHUNKS) // 64 rows per block
#define NPART (N_IMG * CHUNKS)

__global__ __launch_bounds__(256, 8) void dasp_sums_kernel(
    const float* __restrict__ masks, unsigned int* __restrict__ partials) {
    const int blk = blockIdx.x;
    const int img = blk / CHUNKS;
    const int chunk = blk - img * CHUNKS;
    const int r0 = chunk * ROWS;
    const int r1 = r0 + ROWS;

    const int wave = threadIdx.x >> 6;
    const int lane = threadIdx.x & 63;
    const int col0 = wave * 256 + lane * 4; // first of this lane's 4 columns

    const float* base = masks + (size_t)img * H * W;

    const bool isL = (lane == 0);
    const bool isR = (lane == 63);
    // strip-edge halo column (only meaningful on lanes 0 / 63)
    const int hcol = isL ? (col0 - 1) : (col0 + 4);
    const bool hvalid = (isL || isR) && (hcol >= 0) && (hcol < W);

    // fetch one row: 4 binary cols per lane + halo col for edge lanes
    auto fetch = [&](int y, float4& f, float& hf) {
        f = make_float4(0.f, 0.f, 0.f, 0.f);
        hf = 0.f;
        if (y >= 0 && y < H) {
            f = *reinterpret_cast<const float4*>(base + (size_t)y * W + col0);
            if (hvalid) hf = base[(size_t)y * W + hcol];
        }
    };

    float4 fp, fc, fn;
    float hfp, hfc, hfn;
    fetch(r0 - 1, fp, hfp);
    fetch(r0, fc, hfc);
    fetch(r0 + 1, fn, hfn); // 1-deep prefetch: fn always holds raw row y+1

    int bp0 = fp.x > 0.f, bp1 = fp.y > 0.f, bp2 = fp.z > 0.f, bp3 = fp.w > 0.f;
    int bc0 = fc.x > 0.f, bc1 = fc.y > 0.f, bc2 = fc.z > 0.f, bc3 = fc.w > 0.f;
    int hp = hfp > 0.f, hc = hfc > 0.f;

    int area = 0, conn = 0, per = 0;

    for (int y = r0; y < r1; ++y) {
        // prefetch row y+2 (need rows up to r1 inclusive as bottom halo)
        float4 f2;
        float hf2;
        const int y2 = y + 2;
        if (y2 <= r1) {
            fetch(y2, f2, hf2);
        } else {
            f2 = make_float4(0.f, 0.f, 0.f, 0.f);
            hf2 = 0.f;
        }

        const int bn0 = fn.x > 0.f, bn1 = fn.y > 0.f, bn2 = fn.z > 0.f,
                  bn3 = fn.w > 0.f;
        const int hn = hfn > 0.f;

        // vertical column sums over rows y-1,y,y+1
        const int c0 = bp0 + bc0 + bn0;
        const int c1 = bp1 + bc1 + bn1;
        const int c2 = bp2 + bc2 + bn2;
        const int c3 = bp3 + bc3 + bn3;
        const int ch = hp + hc + hn;

        // horizontal neighbors: previous lane's c3, next lane's c0
        int cl = __shfl_up(c3, 1);
        int cr = __shfl_down(c0, 1);
        if (isL) cl = ch; // wave 0 lane 0: ch==0 (hcol invalid) -> image edge
        if (isR) cr = ch;

        // 8-neighbor counts (3x3 box sum minus center)
        const int n0 = cl + c0 + c1 - bc0;
        const int n1 = c0 + c1 + c2 - bc1;
        const int n2 = c1 + c2 + c3 - bc2;
        const int n3 = c2 + c3 + cr - bc3;

        area += bc0 + bc1 + bc2 + bc3;
        conn += n0 * bc0 + n1 * bc1 + n2 * bc2 + n3 * bc3;
        per += max(n0 - 4 * bc0, 0) + max(n1 - 4 * bc1, 0) +
               max(n2 - 4 * bc2, 0) + max(n3 - 4 * bc3, 0);

        // roll rows down
        bp0 = bc0; bp1 = bc1; bp2 = bc2; bp3 = bc3;
        bc0 = bn0; bc1 = bn1; bc2 = bn2; bc3 = bn3;
        hp = hc; hc = hn;
        fn = f2; hfn = hf2;
    }

    // wave butterfly reduction (64 lanes)
    #pragma unroll
    for (int m = 32; m >= 1; m >>= 1) {
        area += __shfl_xor(area, m);
        conn += __shfl_xor(conn, m);
        per += __shfl_xor(per, m);
    }

    __shared__ int sA[4], sC[4], sP[4];
    if (lane == 0) {
        sA[wave] = area;
        sC[wave] = conn;
        sP[wave] = per;
    }
    __syncthreads();
    if (threadIdx.x == 0) {
        const unsigned int a = (unsigned)(sA[0] + sA[1] + sA[2] + sA[3]);
        const unsigned int c = (unsigned)(sC[0] + sC[1] + sC[2] + sC[3]);
        const unsigned int p = (unsigned)(sP[0] + sP[1] + sP[2] + sP[3]);
        partials[blk] = a;
        partials[NPART + blk] = c;
        partials[2 * NPART + blk] = p;
    }
}

__global__ void dasp_score_kernel(const unsigned int* __restrict__ partials,
                                  float* __restrict__ out) {
    const int n = threadIdx.x;
    if (n >= N_IMG) return;
    unsigned int a = 0, c = 0, p = 0;
    #pragma unroll
    for (int k = 0; k < CHUNKS; ++k) {
        a += partials[n * CHUNKS + k];
        c += partials[NPART + n * CHUNKS + k];
        p += partials[2 * NPART + n * CHUNKS + k];
    }
    const float areaf = (float)a;
    const float ratio = areaf / (float)(H * W);
    const float area_score = (ratio >= 0.001f && ratio <= 0.5f) ? 1.0f : 0.1f;
    const float safe = (a > 0) ? areaf : 1.0f;
    const float connf = (float)c;
    const float comp =
        (c > 0) ? fminf(1.0f, 10.0f / (connf / safe + 1e-6f)) : 0.1f;
    const float perf = (float)p;
    const float par = perf / safe;
    const float shape =
        (a > 0) ? ((par <= 100.0f) ? 1.0f
                                   : fmaxf(0.1f, 100.0f / (par + 1e-6f)))
                : 0.1f;
    const float v = 0.4f * area_score + 0.3f * comp + 0.3f * shape;
    out[n] = fmaxf(0.05f, v);
}

extern "C" void kernel_launch(void* const* d_in, const int* in_sizes, int n_in,
                              void* d_out, int out_size, void* d_ws,
                              size_t ws_size, hipStream_t stream) {
    const float* masks = (const float*)d_in[0];
    float* out = (float*)d_out;
    unsigned int* partials = (unsigned int*)d_ws; // 3 * 2048 * 4 B = 24 KB

    dasp_sums_kernel<<<dim3(N_IMG * CHUNKS), dim3(256), 0, stream>>>(masks,
                                                                     partials);
    dasp_score_kernel<<<dim3(1), dim3(128), 0, stream>>>(partials, out);
}

// Round 2
// 677.850 us; speedup vs baseline: 1.0005x; 1.0005x over previous
//
#include <hip/hip_runtime.h>

// DomainAwareStructuralPrior: masks (128,1024,1024) f32 logits -> (128,) f32.
// Pass 1: each WAVE sweeps 32 full-width rows (4 float4 segments/lane/row),
//         binaries packed as bytes-in-u32, horizontal sums via v_sad_u8.
//         All sums are exact integers -> bit-exact vs the fp32 reference.
// Pass 2: 128-thread scoring kernel.

#define N_IMG 128
#define H 1024
#define W 1024
#define WROWS 32                         // rows per wave
#define WAVES_PER_BLOCK 4
#define BROWS (WROWS * WAVES_PER_BLOCK)  // 128 rows per block
#define BLOCKS_PER_IMG (H / BROWS)       // 8
#define NPART (N_IMG * BLOCKS_PER_IMG)   // 1024

static __device__ __forceinline__ unsigned sad8(unsigned a, unsigned b,
                                                unsigned c) {
#if __has_builtin(__builtin_amdgcn_sad_u8)
    return __builtin_amdgcn_sad_u8(a, b, c);
#else
    unsigned s = c;
#pragma unroll
    for (int k = 0; k < 4; ++k) {
        unsigned x = (a >> (8 * k)) & 0xFFu, y = (b >> (8 * k)) & 0xFFu;
        s += (x > y) ? (x - y) : (y - x);
    }
    return s;
#endif
}

__global__ __launch_bounds__(256, 4) void dasp_sums_kernel(
    const float* __restrict__ masks, unsigned* __restrict__ partials) {
    const int blk = blockIdx.x;
    const int img = blk / BLOCKS_PER_IMG;
    const int chunk = blk - img * BLOCKS_PER_IMG;
    const int wave = threadIdx.x >> 6;
    const int lane = threadIdx.x & 63;

    const int y0 = chunk * BROWS + wave * WROWS;  // first compute row
    const int yEnd = y0 + WROWS;                  // bottom halo row index

    const float* __restrict__ base = masks + (size_t)img * (H * W);

    // Fetch one full row: 4 segments, seg s covers cols [s*256, s*256+256),
    // this lane holds cols s*256 + lane*4 .. +3. Rows outside [0,H) -> 0.
    auto fetchRow = [&](int y, float4* f) {
        if (y >= 0 && y < H) {
            const float* row = base + (size_t)y * W + lane * 4;
            f[0] = *reinterpret_cast<const float4*>(row);
            f[1] = *reinterpret_cast<const float4*>(row + 256);
            f[2] = *reinterpret_cast<const float4*>(row + 512);
            f[3] = *reinterpret_cast<const float4*>(row + 768);
        } else {
            f[0] = f[1] = f[2] = f[3] = make_float4(0.f, 0.f, 0.f, 0.f);
        }
    };

    // binary(x) = (x > 0), packed one byte per column: byte j = col j of the
    // lane's 4-col group.
    auto packRow = [&](const float4* f, unsigned* b) {
#pragma unroll
        for (int s = 0; s < 4; ++s) {
            unsigned v = (f[s].x > 0.f) ? 0x00000001u : 0u;
            v |= (f[s].y > 0.f) ? 0x00000100u : 0u;
            v |= (f[s].z > 0.f) ? 0x00010000u : 0u;
            v |= (f[s].w > 0.f) ? 0x01000000u : 0u;
            b[s] = v;
        }
    };

    unsigned bp[4], bc[4];  // packed binary rows y-1, y
    float4 fa[4], fb[4];    // raw rows y+1, y+2 (prefetch depth 2)
    {
        float4 t[4];
        fetchRow(y0 - 1, t);
        packRow(t, bp);
        fetchRow(y0, t);
        packRow(t, bc);
    }
    fetchRow(y0 + 1, fa);
    fetchRow(y0 + 2, fb);

    const bool isL0 = (lane == 0);
    const bool isL63 = (lane == 63);

    unsigned area = 0, conn = 0, A1 = 0, A2 = 0;

#pragma unroll 2
    for (int y = y0; y < yEnd; ++y) {
        // prefetch row y+3 (rows beyond yEnd are never consumed)
        float4 fnew[4];
        if (y + 3 <= yEnd) {
            fetchRow(y + 3, fnew);
        } else {
            fnew[0] = fnew[1] = fnew[2] = fnew[3] =
                make_float4(0.f, 0.f, 0.f, 0.f);
        }

        unsigned bn[4];
        packRow(fa, bn);  // row y+1

        // vertical 3-row column sums, one byte per column (max 3, no carry)
        unsigned c[4];
#pragma unroll
        for (int s = 0; s < 4; ++s) c[s] = bp[s] + bc[s] + bn[s];

#pragma unroll
        for (int s = 0; s < 4; ++s) {
            // left/right neighbor-group column sums via in-wave shuffles
            unsigned cls = __shfl_up(c[s], 1);
            const unsigned bcl = (s > 0) ? __shfl(c[s - 1], 63) : 0u;
            cls = isL0 ? bcl : cls;
            unsigned crs = __shfl_down(c[s], 1);
            const unsigned bcr = (s < 3) ? __shfl(c[s + 1], 0) : 0u;
            crs = isL63 ? bcr : crs;

            const unsigned left = (c[s] << 8) | (cls >> 24);   // c_{j-1}
            const unsigned right = (c[s] >> 8) | (crs << 24);  // c_{j+1}
            // 8-neighbor count per column byte: box sum minus center
            // (max 9 per byte -> no carries; n >= b so sub has no borrows)
            const unsigned n = c[s] + left + right - bc[s];

            const unsigned bmask = (bc[s] << 8) - bc[s];  // b ? 0xFF : 0x00
            area = sad8(bc[s], 0u, area);                 // sum b
            A2 = sad8(n, 0u, A2);                         // sum n
            A1 = sad8(n, bc[s] << 2, A1);                 // sum |n - 4b|
            conn = sad8(n & bmask, 0u, conn);             // sum n*b
        }

#pragma unroll
        for (int s = 0; s < 4; ++s) {
            bp[s] = bc[s];
            bc[s] = bn[s];
            fa[s] = fb[s];
            fb[s] = fnew[s];
        }
    }

    // per-pixel: max(n-4b,0) = (|n-4b| + n - 4b)/2 ; summed per lane (even)
    int a = (int)area;
    int cn = (int)conn;
    int p = (int)((A1 + A2 - 4u * area) >> 1);

#pragma unroll
    for (int m = 32; m >= 1; m >>= 1) {
        a += __shfl_xor(a, m);
        cn += __shfl_xor(cn, m);
        p += __shfl_xor(p, m);
    }

    __shared__ int sA[WAVES_PER_BLOCK], sC[WAVES_PER_BLOCK],
        sP[WAVES_PER_BLOCK];
    if (lane == 0) {
        sA[wave] = a;
        sC[wave] = cn;
        sP[wave] = p;
    }
    __syncthreads();
    if (threadIdx.x == 0) {
        int ta = 0, tc = 0, tp = 0;
#pragma unroll
        for (int wv = 0; wv < WAVES_PER_BLOCK; ++wv) {
            ta += sA[wv];
            tc += sC[wv];
            tp += sP[wv];
        }
        partials[blk] = (unsigned)ta;
        partials[NPART + blk] = (unsigned)tc;
        partials[2 * NPART + blk] = (unsigned)tp;
    }
}

__global__ void dasp_score_kernel(const unsigned* __restrict__ partials,
                                  float* __restrict__ out) {
    const int n = threadIdx.x;
    if (n >= N_IMG) return;
    unsigned a = 0, c = 0, p = 0;
#pragma unroll
    for (int k = 0; k < BLOCKS_PER_IMG; ++k) {
        a += partials[n * BLOCKS_PER_IMG + k];
        c += partials[NPART + n * BLOCKS_PER_IMG + k];
        p += partials[2 * NPART + n * BLOCKS_PER_IMG + k];
    }
    const float areaf = (float)a;
    const float ratio = areaf / (float)(H * W);
    const float area_score = (ratio >= 0.001f && ratio <= 0.5f) ? 1.0f : 0.1f;
    const float safe = (a > 0) ? areaf : 1.0f;
    const float connf = (float)c;
    const float comp =
        (c > 0) ? fminf(1.0f, 10.0f / (connf / safe + 1e-6f)) : 0.1f;
    const float perf = (float)p;
    const float par = perf / safe;
    const float shape =
        (a > 0)
            ? ((par <= 100.0f) ? 1.0f : fmaxf(0.1f, 100.0f / (par + 1e-6f)))
            : 0.1f;
    const float v = 0.4f * area_score + 0.3f * comp + 0.3f * shape;
    out[n] = fmaxf(0.05f, v);
}

extern "C" void kernel_launch(void* const* d_in, const int* in_sizes, int n_in,
                              void* d_out, int out_size, void* d_ws,
                              size_t ws_size, hipStream_t stream) {
    const float* masks = (const float*)d_in[0];
    float* out = (float*)d_out;
    unsigned* partials = (unsigned*)d_ws;  // 3 * 1024 * 4 B = 12 KB

    dasp_sums_kernel<<<dim3(N_IMG * BLOCKS_PER_IMG), dim3(256), 0, stream>>>(
        masks, partials);
    dasp_score_kernel<<<dim3(1), dim3(128), 0, stream>>>(partials, out);
}